// Round 2
// baseline (11805.122 us; speedup 1.0000x reference)
//
#include <hip/hip_runtime.h>
#include <hip/hip_bf16.h>
#include <math.h>

#define NN 100000
#define EE 400000
#define KD 2
#define DD 256
#define ATTD 64
#define LL 3
#define HH1 128
#define HH2 64
#define EPSV 1e-5f
#define SLOPE 0.01f

// ---------------- BatchNorm ----------------
__global__ void bn_stats(const float* __restrict__ x, float* __restrict__ sums) {
    int d = threadIdx.x;               // 256 threads = 256 features
    int r0 = blockIdx.x * 125;         // 800 blocks * 125 rows = 100000
    float s = 0.f, sq = 0.f;
    for (int r = r0; r < r0 + 125; ++r) {
        float v = x[(size_t)r * DD + d];
        s += v; sq += v * v;
    }
    atomicAdd(&sums[d], s);
    atomicAdd(&sums[DD + d], sq);
}

__global__ void bn_apply(const float* __restrict__ x, const float* __restrict__ sums,
                         const float* __restrict__ gamma, const float* __restrict__ beta,
                         float* __restrict__ h) {
    size_t i = (size_t)blockIdx.x * blockDim.x + threadIdx.x;  // vec4 index, exact cover
    const float inv_n = 1.f / NN;
    int dq = (int)(i & 63) * 4;        // D/4 = 64
    float4 xv = ((const float4*)x)[i];
    float4 hv;
    float* xp = (float*)&xv; float* hp = (float*)&hv;
#pragma unroll
    for (int j = 0; j < 4; ++j) {
        int d = dq + j;
        float mu = sums[d] * inv_n;
        float var = sums[DD + d] * inv_n - mu * mu;
        float inv = rsqrtf(var + EPSV);
        hp[j] = (xp[j] - mu) * inv * gamma[d] + beta[d];
    }
    ((float4*)h)[i] = hv;
}

// ---------------- degree / norm precompute ----------------
__global__ void deg_accum(const int* __restrict__ ei, const float* __restrict__ w,
                          float* __restrict__ deg) {
    int i = blockIdx.x * blockDim.x + threadIdx.x;
    if (i >= KD * EE) return;
    int k = i / EE, e = i - k * EE;
    int col = ei[(size_t)k * 2 * EE + EE + e];
    atomicAdd(&deg[k * NN + col], w[i]);
}

__global__ void dinv_kernel(float* __restrict__ d) {
    int i = blockIdx.x * blockDim.x + threadIdx.x;
    if (i >= KD * NN) return;
    float v = d[i];
    d[i] = v > 0.f ? 1.f / sqrtf(v) : 0.f;
}

__global__ void norm_kernel(const int* __restrict__ ei, const float* __restrict__ w,
                            const float* __restrict__ dinv, float* __restrict__ nrm) {
    int i = blockIdx.x * blockDim.x + threadIdx.x;
    if (i >= KD * EE) return;
    int k = i / EE, e = i - k * EE;
    const int* eik = ei + (size_t)k * 2 * EE;
    int row = eik[e], col = eik[EE + e];
    nrm[i] = dinv[k * NN + col] * w[i] * dinv[k * NN + row];
}

// ---------------- fp32 tiled GEMM  C = A(MxK) * B(KxN) [+bias][act] ----------------
// act: 0 = none, 1 = leaky-relu.  If Cb != nullptr, store bf16 to Cb instead of C.
#define BM 64
#define BN 64
#define BK 32
__global__ __launch_bounds__(256) void gemm_f32(
        const float* __restrict__ A, const float* __restrict__ B,
        const float* __restrict__ bias, float* __restrict__ C,
        __hip_bfloat16* __restrict__ Cb,
        int M, int Kd, int Nc, int act) {
    __shared__ float As[BM][BK + 1];
    __shared__ float Bs[BK][BN + 1];
    int bm = blockIdx.x * BM, bn = blockIdx.y * BN;
    int tid = threadIdx.x;
    int tr = tid >> 4, tc = tid & 15;
    float acc[4][4] = {{0.f}};
    for (int k0 = 0; k0 < Kd; k0 += BK) {
        for (int t = tid; t < BM * BK; t += 256) {
            int r = t >> 5, c = t & 31;
            int gr = bm + r;
            As[r][c] = (gr < M) ? A[(size_t)gr * Kd + k0 + c] : 0.f;
        }
        for (int t = tid; t < BK * BN; t += 256) {
            int r = t >> 6, c = t & 63;
            Bs[r][c] = B[(size_t)(k0 + r) * Nc + bn + c];
        }
        __syncthreads();
#pragma unroll
        for (int kk = 0; kk < BK; ++kk) {
            float a[4], b[4];
#pragma unroll
            for (int i = 0; i < 4; ++i) a[i] = As[tr + 16 * i][kk];
#pragma unroll
            for (int j = 0; j < 4; ++j) b[j] = Bs[kk][tc + 16 * j];
#pragma unroll
            for (int i = 0; i < 4; ++i)
#pragma unroll
                for (int j = 0; j < 4; ++j) acc[i][j] += a[i] * b[j];
        }
        __syncthreads();
    }
#pragma unroll
    for (int i = 0; i < 4; ++i) {
        int gr = bm + tr + 16 * i;
        if (gr >= M) continue;
#pragma unroll
        for (int j = 0; j < 4; ++j) {
            int gc = bn + tc + 16 * j;
            float v = acc[i][j];
            if (bias) v += bias[gc];
            if (act == 1) v = v > 0.f ? v : SLOPE * v;
            if (Cb) Cb[(size_t)gr * Nc + gc] = __float2bfloat16(v);
            else    C[(size_t)gr * Nc + gc] = v;
        }
    }
}

// ---------------- scatter aggregation: xs[k,col,:] += norm * xw[row,:] ----------------
// xw is bf16 (N x D), xs is fp32 (K x N x D)
__global__ __launch_bounds__(256) void scatter_agg(
        const int* __restrict__ ei, const float* __restrict__ nrm,
        const __hip_bfloat16* __restrict__ xw, float* __restrict__ xs) {
    int widx = blockIdx.x * 4 + (threadIdx.x >> 6);   // one wave per edge
    int lane = threadIdx.x & 63;
    if (widx >= KD * EE) return;
    float nv = nrm[widx];
    if (nv == 0.f) return;
    int k = widx / EE, e = widx - k * EE;
    const int* eik = ei + (size_t)k * 2 * EE;
    int row = eik[e], col = eik[EE + e];
    const __hip_bfloat162* p =
        (const __hip_bfloat162*)(xw + (size_t)row * DD + lane * 4);
    float2 f0 = __bfloat1622float2(p[0]);
    float2 f1 = __bfloat1622float2(p[1]);
    float* dst = xs + ((size_t)k * NN + col) * DD + lane * 4;
    atomicAdd(dst + 0, f0.x * nv);
    atomicAdd(dst + 1, f0.y * nv);
    atomicAdd(dst + 2, f1.x * nv);
    atomicAdd(dst + 3, f1.y * nv);
}

// ---------------- fused keys = tanh((xs+b_gcn) @ Wk + b), sim = keys . q ----------------
__global__ __launch_bounds__(256) void att_sim(
        const float* __restrict__ xs, const float* __restrict__ W,   // (K,D,ATT) this layer
        const float* __restrict__ b,                                  // (K,ATT)
        const float* __restrict__ q,                                  // (K,ATT)
        const float* __restrict__ gcnb,                               // (D)
        float* __restrict__ sim) {
    __shared__ float Ws[DD * ATTD];   // 64 KB exactly
    int k = blockIdx.y;
    int tid = threadIdx.x;
    for (int t = tid; t < DD * ATTD; t += 256) Ws[t] = W[(size_t)k * DD * ATTD + t];
    __syncthreads();
    int wave = tid >> 6, lane = tid & 63;
    // fold gcn_b: contribution to acc is sum_d gcnb[d]*W[d][lane] — constant per lane
    float bb = b[k * ATTD + lane];
    for (int d = 0; d < DD; ++d) bb += gcnb[d] * Ws[d * ATTD + lane];
    float qq = q[k * ATTD + lane];
    for (int n = blockIdx.x * 4 + wave; n < NN; n += gridDim.x * 4) {
        const float* xrow = xs + ((size_t)k * NN + n) * DD;
        float acc = bb;
#pragma unroll 8
        for (int d = 0; d < DD; ++d)
            acc += xrow[d] * Ws[d * ATTD + lane];
        float s = tanhf(acc) * qq;
#pragma unroll
        for (int off = 32; off > 0; off >>= 1) s += __shfl_xor(s, off, 64);
        if (lane == 0) sim[(size_t)k * NN + n] = s;
    }
}

// ---------------- softmax over K=2 + combine + relu, folds gcn_b ----------------
// NOTE: h may alias xs[k=0] — safe: each thread reads index i then writes index i.
__global__ void combine_relu(const float* __restrict__ xs, const float* __restrict__ sim,
                             const float* __restrict__ gcnb, float* __restrict__ h) {
    size_t i = (size_t)blockIdx.x * blockDim.x + threadIdx.x;  // vec4 index
    int n = (int)(i >> 6);
    int dq = (int)(i & 63);
    float s0 = sim[n], s1 = sim[NN + n];
    float m = fmaxf(s0, s1);
    float e0 = expf(s0 - m), e1 = expf(s1 - m);
    float inv = 1.f / (e0 + e1);
    float a0 = e0 * inv, a1 = e1 * inv;
    float4 v0 = ((const float4*)xs)[i];
    float4 v1 = ((const float4*)(xs + (size_t)NN * DD))[i];
    float4 bv = ((const float4*)gcnb)[dq];
    float4 r;
    r.x = fmaxf(0.f, a0 * v0.x + a1 * v1.x + bv.x);
    r.y = fmaxf(0.f, a0 * v0.y + a1 * v1.y + bv.y);
    r.z = fmaxf(0.f, a0 * v0.z + a1 * v1.z + bv.z);
    r.w = fmaxf(0.f, a0 * v0.w + a1 * v1.w + bv.w);
    ((float4*)h)[i] = r;
}

extern "C" void kernel_launch(void* const* d_in, const int* in_sizes, int n_in,
                              void* d_out, int out_size, void* d_ws, size_t ws_size,
                              hipStream_t stream) {
    const float* x     = (const float*)d_in[0];
    const int*   ei    = (const int*)d_in[1];
    const float* ew    = (const float*)d_in[2];
    const float* gamma = (const float*)d_in[3];
    const float* beta  = (const float*)d_in[4];
    const float* gcn_W = (const float*)d_in[5];
    const float* gcn_b = (const float*)d_in[6];
    const float* att_W = (const float*)d_in[7];
    const float* att_b = (const float*)d_in[8];
    const float* att_q = (const float*)d_in[9];
    const float* pW1   = (const float*)d_in[10];
    const float* pb1   = (const float*)d_in[11];
    const float* pW2   = (const float*)d_in[12];
    const float* pb2   = (const float*)d_in[13];
    float* out = (float*)d_out;

    // ---- workspace layout (~261 MB total) ----
    // [0, 204.8 MB)      : xs fp32 (K,N,D);  h fp32 aliases xs[k=0]
    // [204.8, 256 MB)    : xw bf16 (N,D)  — also reused as fp32 (N,H1) proj1 temp
    // then dinv, nrm, sim, bnsums
    char* wsb = (char*)d_ws;
    size_t off = 0;
    auto alloc = [&](size_t bytes) -> void* {
        void* p = wsb + off;
        off += (bytes + 255) & ~(size_t)255;
        return p;
    };
    float*          xs    = (float*)alloc((size_t)KD * NN * DD * 4);   // 204.8 MB
    float*          h     = xs;                                        // alias xs[k=0]
    __hip_bfloat16* xw    = (__hip_bfloat16*)alloc((size_t)NN * DD * 2); // 51.2 MB
    float*          p1tmp = (float*)xw;                                // N*H1*4 = 51.2 MB, exact reuse
    float*          dinv  = (float*)alloc((size_t)KD * NN * 4);
    float*          nrm   = (float*)alloc((size_t)KD * EE * 4);
    float*          sim   = (float*)alloc((size_t)KD * NN * 4);
    float*          bnsums= (float*)alloc(2 * DD * 4);

    // BatchNorm -> h
    hipMemsetAsync(bnsums, 0, 2 * DD * 4, stream);
    bn_stats<<<800, 256, 0, stream>>>(x, bnsums);
    bn_apply<<<25000, 256, 0, stream>>>(x, bnsums, gamma, beta, h);

    // degree / norm (layer-invariant)
    hipMemsetAsync(dinv, 0, (size_t)KD * NN * 4, stream);
    deg_accum<<<(KD * EE + 255) / 256, 256, 0, stream>>>(ei, ew, dinv);
    dinv_kernel<<<(KD * NN + 255) / 256, 256, 0, stream>>>(dinv);
    norm_kernel<<<(KD * EE + 255) / 256, 256, 0, stream>>>(ei, ew, dinv, nrm);

    for (int l = 0; l < LL; ++l) {
        // xw(bf16) = h @ gcn_W[l]   (h fully consumed before xs memset below)
        dim3 g1((NN + BM - 1) / BM, DD / BN);
        gemm_f32<<<g1, 256, 0, stream>>>(h, gcn_W + (size_t)l * DD * DD, nullptr,
                                         nullptr, xw, NN, DD, DD, 0);
        hipMemsetAsync(xs, 0, (size_t)KD * NN * DD * 4, stream);
        scatter_agg<<<(KD * EE + 3) / 4, 256, 0, stream>>>(ei, nrm, xw, xs);
        dim3 g2(512, KD);
        att_sim<<<g2, 256, 0, stream>>>(xs, att_W + (size_t)l * KD * DD * ATTD,
                                        att_b + l * KD * ATTD, att_q + l * KD * ATTD,
                                        gcn_b + l * DD, sim);
        combine_relu<<<25000, 256, 0, stream>>>(xs, sim, gcn_b + l * DD, h);
    }

    // projection head
    dim3 gp1((NN + BM - 1) / BM, HH1 / BN);
    gemm_f32<<<gp1, 256, 0, stream>>>(h, pW1, pb1, p1tmp, nullptr, NN, DD, HH1, 1);
    dim3 gp2((NN + BM - 1) / BM, HH2 / BN);
    gemm_f32<<<gp2, 256, 0, stream>>>(p1tmp, pW2, pb2, out, nullptr, NN, HH1, HH2, 1);
}

// Round 3
// 4622.368 us; speedup vs baseline: 2.5539x; 2.5539x over previous
//
#include <hip/hip_runtime.h>
#include <hip/hip_bf16.h>
#include <math.h>

#define NN 100000
#define EE 400000
#define KD 2
#define DD 256
#define ATTD 64
#define LL 3
#define HH1 128
#define HH2 64
#define EPSV 1e-5f
#define SLOPE 0.01f
#define KN (KD * NN)

// ---------------- BatchNorm ----------------
__global__ void bn_stats(const float* __restrict__ x, float* __restrict__ sums) {
    int d = threadIdx.x;               // 256 threads = 256 features
    int r0 = blockIdx.x * 125;         // 800 blocks * 125 rows = 100000
    float s = 0.f, sq = 0.f;
    for (int r = r0; r < r0 + 125; ++r) {
        float v = x[(size_t)r * DD + d];
        s += v; sq += v * v;
    }
    atomicAdd(&sums[d], s);
    atomicAdd(&sums[DD + d], sq);
}

__global__ void bn_apply(const float* __restrict__ x, const float* __restrict__ sums,
                         const float* __restrict__ gamma, const float* __restrict__ beta,
                         float* __restrict__ h) {
    size_t i = (size_t)blockIdx.x * blockDim.x + threadIdx.x;  // vec4 index, exact cover
    const float inv_n = 1.f / NN;
    int dq = (int)(i & 63) * 4;        // D/4 = 64
    float4 xv = ((const float4*)x)[i];
    float4 hv;
    float* xp = (float*)&xv; float* hp = (float*)&hv;
#pragma unroll
    for (int j = 0; j < 4; ++j) {
        int d = dq + j;
        float mu = sums[d] * inv_n;
        float var = sums[DD + d] * inv_n - mu * mu;
        float inv = rsqrtf(var + EPSV);
        hp[j] = (xp[j] - mu) * inv * gamma[d] + beta[d];
    }
    ((float4*)h)[i] = hv;
}

// ---------------- degree ----------------
__global__ void deg_accum(const int* __restrict__ ei, const float* __restrict__ w,
                          float* __restrict__ deg) {
    int i = blockIdx.x * blockDim.x + threadIdx.x;
    if (i >= KD * EE) return;
    int k = i / EE, e = i - k * EE;
    int col = ei[(size_t)k * 2 * EE + EE + e];
    atomicAdd(&deg[k * NN + col], w[i]);
}

__global__ void dinv_kernel(float* __restrict__ d) {
    int i = blockIdx.x * blockDim.x + threadIdx.x;
    if (i >= KD * NN) return;
    float v = d[i];
    d[i] = v > 0.f ? 1.f / sqrtf(v) : 0.f;
}

// ---------------- CSR build (by destination col, per k) ----------------
__global__ void csr_count(const int* __restrict__ ei, int* __restrict__ starts) {
    int i = blockIdx.x * blockDim.x + threadIdx.x;
    if (i >= KD * EE) return;
    int k = i / EE, e = i - k * EE;
    int col = ei[(size_t)k * 2 * EE + EE + e];
    atomicAdd(&starts[k * NN + col], 1);
}

// in-place exclusive scan of starts[0..KN), single block of 256 threads
#define SCHUNK 782   // 256*782 = 200192 >= KN
__global__ void csr_scan(int* __restrict__ starts) {
    __shared__ int sums[256];
    int t = threadIdx.x;
    int base = t * SCHUNK;
    int s = 0;
    for (int i = 0; i < SCHUNK; ++i) {
        int idx = base + i;
        if (idx < KN) s += starts[idx];
    }
    sums[t] = s;
    __syncthreads();
    if (t == 0) {
        int run = 0;
        for (int j = 0; j < 256; ++j) { int v = sums[j]; sums[j] = run; run += v; }
    }
    __syncthreads();
    int run = sums[t];
    for (int i = 0; i < SCHUNK; ++i) {
        int idx = base + i;
        if (idx < KN) { int v = starts[idx]; starts[idx] = run; run += v; }
    }
}

// fill buckets; folds norm.  Uses atomicAdd on starts => afterwards
// starts[i] == original starts[i+1]  (end-pointer form).
__global__ void csr_fill(const int* __restrict__ ei, const float* __restrict__ w,
                         const float* __restrict__ dinv,
                         int* __restrict__ starts, int2* __restrict__ edata) {
    int i = blockIdx.x * blockDim.x + threadIdx.x;
    if (i >= KD * EE) return;
    int k = i / EE, e = i - k * EE;
    const int* eik = ei + (size_t)k * 2 * EE;
    int row = eik[e], col = eik[EE + e];
    float nv = dinv[k * NN + col] * w[i] * dinv[k * NN + row];
    int pos = atomicAdd(&starts[k * NN + col], 1);
    edata[pos] = make_int2(row, __float_as_int(nv));
}

// ---------------- gather aggregation: xs[widx,:] = sum_e norm_e * xw[row_e,:] ----------------
// one wave per (k,node); starts is in end-pointer form (see csr_fill)
__global__ __launch_bounds__(256) void gather_agg(
        const int* __restrict__ starts, const int2* __restrict__ edata,
        const __hip_bfloat16* __restrict__ xw, float* __restrict__ xs) {
    int widx = blockIdx.x * 4 + (threadIdx.x >> 6);
    if (widx >= KN) return;
    int lane = threadIdx.x & 63;
    int begin = widx ? starts[widx - 1] : 0;
    int end = starts[widx];
    float4 acc = make_float4(0.f, 0.f, 0.f, 0.f);
    for (int e = begin; e < end; ++e) {
        int2 ed = edata[e];
        float nv = __int_as_float(ed.y);
        const __hip_bfloat162* p =
            (const __hip_bfloat162*)(xw + (size_t)ed.x * DD + lane * 4);
        float2 f0 = __bfloat1622float2(p[0]);
        float2 f1 = __bfloat1622float2(p[1]);
        acc.x += nv * f0.x; acc.y += nv * f0.y;
        acc.z += nv * f1.x; acc.w += nv * f1.y;
    }
    ((float4*)(xs + (size_t)widx * DD))[lane] = acc;
}

// ---------------- fp32 tiled GEMM  C = A(MxK) * B(KxN) [+bias][act] ----------------
#define BM 64
#define BN 64
#define BK 32
__global__ __launch_bounds__(256) void gemm_f32(
        const float* __restrict__ A, const float* __restrict__ B,
        const float* __restrict__ bias, float* __restrict__ C,
        __hip_bfloat16* __restrict__ Cb,
        int M, int Kd, int Nc, int act) {
    __shared__ float As[BM][BK + 1];
    __shared__ float Bs[BK][BN + 1];
    int bm = blockIdx.x * BM, bn = blockIdx.y * BN;
    int tid = threadIdx.x;
    int tr = tid >> 4, tc = tid & 15;
    float acc[4][4] = {{0.f}};
    for (int k0 = 0; k0 < Kd; k0 += BK) {
        for (int t = tid; t < BM * BK; t += 256) {
            int r = t >> 5, c = t & 31;
            int gr = bm + r;
            As[r][c] = (gr < M) ? A[(size_t)gr * Kd + k0 + c] : 0.f;
        }
        for (int t = tid; t < BK * BN; t += 256) {
            int r = t >> 6, c = t & 63;
            Bs[r][c] = B[(size_t)(k0 + r) * Nc + bn + c];
        }
        __syncthreads();
#pragma unroll
        for (int kk = 0; kk < BK; ++kk) {
            float a[4], b[4];
#pragma unroll
            for (int i = 0; i < 4; ++i) a[i] = As[tr + 16 * i][kk];
#pragma unroll
            for (int j = 0; j < 4; ++j) b[j] = Bs[kk][tc + 16 * j];
#pragma unroll
            for (int i = 0; i < 4; ++i)
#pragma unroll
                for (int j = 0; j < 4; ++j) acc[i][j] += a[i] * b[j];
        }
        __syncthreads();
    }
#pragma unroll
    for (int i = 0; i < 4; ++i) {
        int gr = bm + tr + 16 * i;
        if (gr >= M) continue;
#pragma unroll
        for (int j = 0; j < 4; ++j) {
            int gc = bn + tc + 16 * j;
            float v = acc[i][j];
            if (bias) v += bias[gc];
            if (act == 1) v = v > 0.f ? v : SLOPE * v;
            if (Cb) Cb[(size_t)gr * Nc + gc] = __float2bfloat16(v);
            else    C[(size_t)gr * Nc + gc] = v;
        }
    }
}

// ---------------- fused keys = tanh((xs+b_gcn) @ Wk + b), sim = keys . q ----------------
__global__ __launch_bounds__(256) void att_sim(
        const float* __restrict__ xs, const float* __restrict__ W,   // (K,D,ATT) this layer
        const float* __restrict__ b,                                  // (K,ATT)
        const float* __restrict__ q,                                  // (K,ATT)
        const float* __restrict__ gcnb,                               // (D)
        float* __restrict__ sim) {
    __shared__ float Ws[DD * ATTD];   // 64 KB exactly
    int k = blockIdx.y;
    int tid = threadIdx.x;
    for (int t = tid; t < DD * ATTD; t += 256) Ws[t] = W[(size_t)k * DD * ATTD + t];
    __syncthreads();
    int wave = tid >> 6, lane = tid & 63;
    // fold gcn_b: contribution to acc is sum_d gcnb[d]*W[d][lane] — constant per lane
    float bb = b[k * ATTD + lane];
    for (int d = 0; d < DD; ++d) bb += gcnb[d] * Ws[d * ATTD + lane];
    float qq = q[k * ATTD + lane];
    for (int n = blockIdx.x * 4 + wave; n < NN; n += gridDim.x * 4) {
        const float* xrow = xs + ((size_t)k * NN + n) * DD;
        float acc = bb;
#pragma unroll 8
        for (int d = 0; d < DD; ++d)
            acc += xrow[d] * Ws[d * ATTD + lane];
        float s = tanhf(acc) * qq;
#pragma unroll
        for (int off = 32; off > 0; off >>= 1) s += __shfl_xor(s, off, 64);
        if (lane == 0) sim[(size_t)k * NN + n] = s;
    }
}

// ---------------- softmax over K=2 + combine + relu, folds gcn_b ----------------
// NOTE: h may alias xs[k=0] — safe: each thread reads index i then writes index i.
__global__ void combine_relu(const float* __restrict__ xs, const float* __restrict__ sim,
                             const float* __restrict__ gcnb, float* __restrict__ h) {
    size_t i = (size_t)blockIdx.x * blockDim.x + threadIdx.x;  // vec4 index
    int n = (int)(i >> 6);
    int dq = (int)(i & 63);
    float s0 = sim[n], s1 = sim[NN + n];
    float m = fmaxf(s0, s1);
    float e0 = expf(s0 - m), e1 = expf(s1 - m);
    float inv = 1.f / (e0 + e1);
    float a0 = e0 * inv, a1 = e1 * inv;
    float4 v0 = ((const float4*)xs)[i];
    float4 v1 = ((const float4*)(xs + (size_t)NN * DD))[i];
    float4 bv = ((const float4*)gcnb)[dq];
    float4 r;
    r.x = fmaxf(0.f, a0 * v0.x + a1 * v1.x + bv.x);
    r.y = fmaxf(0.f, a0 * v0.y + a1 * v1.y + bv.y);
    r.z = fmaxf(0.f, a0 * v0.z + a1 * v1.z + bv.z);
    r.w = fmaxf(0.f, a0 * v0.w + a1 * v1.w + bv.w);
    ((float4*)h)[i] = r;
}

extern "C" void kernel_launch(void* const* d_in, const int* in_sizes, int n_in,
                              void* d_out, int out_size, void* d_ws, size_t ws_size,
                              hipStream_t stream) {
    const float* x     = (const float*)d_in[0];
    const int*   ei    = (const int*)d_in[1];
    const float* ew    = (const float*)d_in[2];
    const float* gamma = (const float*)d_in[3];
    const float* beta  = (const float*)d_in[4];
    const float* gcn_W = (const float*)d_in[5];
    const float* gcn_b = (const float*)d_in[6];
    const float* att_W = (const float*)d_in[7];
    const float* att_b = (const float*)d_in[8];
    const float* att_q = (const float*)d_in[9];
    const float* pW1   = (const float*)d_in[10];
    const float* pb1   = (const float*)d_in[11];
    const float* pW2   = (const float*)d_in[12];
    const float* pb2   = (const float*)d_in[13];
    float* out = (float*)d_out;

    // ---- workspace layout (~265.6 MB total, fits 256 MiB) ----
    char* wsb = (char*)d_ws;
    size_t off = 0;
    auto alloc = [&](size_t bytes) -> void* {
        void* p = wsb + off;
        off += (bytes + 255) & ~(size_t)255;
        return p;
    };
    float*          xs    = (float*)alloc((size_t)KD * NN * DD * 4);     // 204.8 MB
    float*          h     = xs;                                          // alias xs[k=0]
    __hip_bfloat16* xw    = (__hip_bfloat16*)alloc((size_t)NN * DD * 2); // 51.2 MB
    float*          p1tmp = (float*)xw;                                  // N*H1*4, exact reuse
    float*          dinv  = (float*)alloc((size_t)KN * 4);               // 0.8 MB
    float*          sim   = (float*)alloc((size_t)KN * 4);               // 0.8 MB
    int*            starts= (int*)alloc(((size_t)KN + 1) * 4);           // 0.8 MB
    int2*           edata = (int2*)alloc((size_t)KD * EE * 8);           // 6.4 MB
    float*          bnsums= (float*)alloc(2 * DD * 4);

    // BatchNorm -> h
    hipMemsetAsync(bnsums, 0, 2 * DD * 4, stream);
    bn_stats<<<800, 256, 0, stream>>>(x, bnsums);
    bn_apply<<<25000, 256, 0, stream>>>(x, bnsums, gamma, beta, h);

    // degree / dinv (layer-invariant)
    hipMemsetAsync(dinv, 0, (size_t)KN * 4, stream);
    deg_accum<<<(KD * EE + 255) / 256, 256, 0, stream>>>(ei, ew, dinv);
    dinv_kernel<<<(KN + 255) / 256, 256, 0, stream>>>(dinv);

    // CSR build (once)
    hipMemsetAsync(starts, 0, ((size_t)KN + 1) * 4, stream);
    csr_count<<<(KD * EE + 255) / 256, 256, 0, stream>>>(ei, starts);
    csr_scan<<<1, 256, 0, stream>>>(starts);
    csr_fill<<<(KD * EE + 255) / 256, 256, 0, stream>>>(ei, ew, dinv, starts, edata);

    for (int l = 0; l < LL; ++l) {
        // xw(bf16) = h @ gcn_W[l]   (h fully consumed before gather overwrites xs)
        dim3 g1((NN + BM - 1) / BM, DD / BN);
        gemm_f32<<<g1, 256, 0, stream>>>(h, gcn_W + (size_t)l * DD * DD, nullptr,
                                         nullptr, xw, NN, DD, DD, 0);
        gather_agg<<<(KN + 3) / 4, 256, 0, stream>>>(starts, edata, xw, xs);
        dim3 g2(512, KD);
        att_sim<<<g2, 256, 0, stream>>>(xs, att_W + (size_t)l * KD * DD * ATTD,
                                        att_b + l * KD * ATTD, att_q + l * KD * ATTD,
                                        gcn_b + l * DD, sim);
        combine_relu<<<25000, 256, 0, stream>>>(xs, sim, gcn_b + l * DD, h);
    }

    // projection head
    dim3 gp1((NN + BM - 1) / BM, HH1 / BN);
    gemm_f32<<<gp1, 256, 0, stream>>>(h, pW1, pb1, p1tmp, nullptr, NN, DD, HH1, 1);
    dim3 gp2((NN + BM - 1) / BM, HH2 / BN);
    gemm_f32<<<gp2, 256, 0, stream>>>(p1tmp, pW2, pb2, out, nullptr, NN, HH1, HH2, 1);
}

// Round 4
// 1732.419 us; speedup vs baseline: 6.8142x; 2.6682x over previous
//
#include <hip/hip_runtime.h>
#include <hip/hip_bf16.h>
#include <math.h>

#define NN 100000
#define EE 400000
#define KD 2
#define DD 256
#define ATTD 64
#define LL 3
#define HH1 128
#define HH2 64
#define EPSV 1e-5f
#define SLOPE 0.01f
#define KN (KD * NN)

typedef short short8 __attribute__((ext_vector_type(8)));
typedef float floatx4 __attribute__((ext_vector_type(4)));
typedef unsigned short u16;
typedef unsigned int u32;

__device__ __forceinline__ u16 f2bf(float f) {
    u32 u = __float_as_uint(f);
    return (u16)((u + 0x7fffu + ((u >> 16) & 1u)) >> 16);
}
__device__ __forceinline__ float bf2f(u16 h) {
    return __uint_as_float((u32)h << 16);
}

// ---------------- BatchNorm ----------------
__global__ void bn_stats(const float* __restrict__ x, float* __restrict__ sums) {
    int d = threadIdx.x;
    int r0 = blockIdx.x * 125;
    float s = 0.f, sq = 0.f;
    for (int r = r0; r < r0 + 125; ++r) {
        float v = x[(size_t)r * DD + d];
        s += v; sq += v * v;
    }
    atomicAdd(&sums[d], s);
    atomicAdd(&sums[DD + d], sq);
}

__global__ void bn_apply(const float* __restrict__ x, const float* __restrict__ sums,
                         const float* __restrict__ gamma, const float* __restrict__ beta,
                         float* __restrict__ h) {
    size_t i = (size_t)blockIdx.x * blockDim.x + threadIdx.x;
    const float inv_n = 1.f / NN;
    int dq = (int)(i & 63) * 4;
    float4 xv = ((const float4*)x)[i];
    float4 hv;
    float* xp = (float*)&xv; float* hp = (float*)&hv;
#pragma unroll
    for (int j = 0; j < 4; ++j) {
        int d = dq + j;
        float mu = sums[d] * inv_n;
        float var = sums[DD + d] * inv_n - mu * mu;
        float inv = rsqrtf(var + EPSV);
        hp[j] = (xp[j] - mu) * inv * gamma[d] + beta[d];
    }
    ((float4*)h)[i] = hv;
}

// ---------------- degree ----------------
__global__ void deg_accum(const int* __restrict__ ei, const float* __restrict__ w,
                          float* __restrict__ deg) {
    int i = blockIdx.x * blockDim.x + threadIdx.x;
    if (i >= KD * EE) return;
    int k = i / EE, e = i - k * EE;
    int col = ei[(size_t)k * 2 * EE + EE + e];
    atomicAdd(&deg[k * NN + col], w[i]);
}

__global__ void dinv_kernel(float* __restrict__ d) {
    int i = blockIdx.x * blockDim.x + threadIdx.x;
    if (i >= KD * NN) return;
    float v = d[i];
    d[i] = v > 0.f ? 1.f / sqrtf(v) : 0.f;
}

// ---------------- CSR build ----------------
__global__ void csr_count(const int* __restrict__ ei, int* __restrict__ starts) {
    int i = blockIdx.x * blockDim.x + threadIdx.x;
    if (i >= KD * EE) return;
    int k = i / EE, e = i - k * EE;
    int col = ei[(size_t)k * 2 * EE + EE + e];
    atomicAdd(&starts[k * NN + col], 1);
}

#define SCHUNK 782
__global__ void csr_scan(int* __restrict__ starts) {
    __shared__ int sums[256];
    int t = threadIdx.x;
    int base = t * SCHUNK;
    int s = 0;
    for (int i = 0; i < SCHUNK; ++i) {
        int idx = base + i;
        if (idx < KN) s += starts[idx];
    }
    sums[t] = s;
    __syncthreads();
    if (t == 0) {
        int run = 0;
        for (int j = 0; j < 256; ++j) { int v = sums[j]; sums[j] = run; run += v; }
    }
    __syncthreads();
    int run = sums[t];
    for (int i = 0; i < SCHUNK; ++i) {
        int idx = base + i;
        if (idx < KN) { int v = starts[idx]; starts[idx] = run; run += v; }
    }
}

__global__ void csr_fill(const int* __restrict__ ei, const float* __restrict__ w,
                         const float* __restrict__ dinv,
                         int* __restrict__ starts, int2* __restrict__ edata) {
    int i = blockIdx.x * blockDim.x + threadIdx.x;
    if (i >= KD * EE) return;
    int k = i / EE, e = i - k * EE;
    const int* eik = ei + (size_t)k * 2 * EE;
    int row = eik[e], col = eik[EE + e];
    float nv = dinv[k * NN + col] * w[i] * dinv[k * NN + row];
    int pos = atomicAdd(&starts[k * NN + col], 1);
    edata[pos] = make_int2(row, __float_as_int(nv));
}

// ---------------- gather aggregation ----------------
__global__ __launch_bounds__(256) void gather_agg(
        const int* __restrict__ starts, const int2* __restrict__ edata,
        const __hip_bfloat16* __restrict__ xw, float* __restrict__ xs) {
    int widx = blockIdx.x * 4 + (threadIdx.x >> 6);
    if (widx >= KN) return;
    int lane = threadIdx.x & 63;
    int begin = widx ? starts[widx - 1] : 0;
    int end = starts[widx];
    float4 acc = make_float4(0.f, 0.f, 0.f, 0.f);
    for (int e = begin; e < end; ++e) {
        int2 ed = edata[e];
        float nv = __int_as_float(ed.y);
        const __hip_bfloat162* p =
            (const __hip_bfloat162*)(xw + (size_t)ed.x * DD + lane * 4);
        float2 f0 = __bfloat1622float2(p[0]);
        float2 f1 = __bfloat1622float2(p[1]);
        acc.x += nv * f0.x; acc.y += nv * f0.y;
        acc.z += nv * f1.x; acc.w += nv * f1.y;
    }
    ((float4*)(xs + (size_t)widx * DD))[lane] = acc;
}

// ---------------- weight convert + transpose: Wt[n][k] = bf16(W[k][n]) ----------------
__global__ void wconv(const float* __restrict__ W, u16* __restrict__ Wt, int Kd, int Nc) {
    int i = blockIdx.x * 256 + threadIdx.x;
    if (i >= Kd * Nc) return;
    int kk = i / Nc, n = i - kk * Nc;
    Wt[(size_t)n * Kd + kk] = f2bf(W[i]);
}

// ---------------- fold gcn_b into attention bias ----------------
// batt[lk][a] = att_b[lk][a] + sum_d gcn_b[l][d] * att_W[lk][d][a]
__global__ void att_bias_fold(const float* __restrict__ attW, const float* __restrict__ attb,
                              const float* __restrict__ gcnb, float* __restrict__ batt) {
    int lk = blockIdx.x;          // 0..5
    int a = threadIdx.x;          // 0..63
    int l = lk >> 1;
    const float* W = attW + (size_t)lk * DD * ATTD;
    const float* gb = gcnb + l * DD;
    float s = attb[lk * ATTD + a];
    for (int d = 0; d < DD; ++d) s += gb[d] * W[d * ATTD + a];
    batt[lk * ATTD + a] = s;
}

// ---------------- MFMA GEMM ----------------
// C(M x Nc) = A(fp32, M x Kd) @ B(bf16 transposed: Bt[n][k], Nc x Kd)
// Tile: BM=128, BN_=64|128, BK=32. 4 waves in 2x2.
// SPLIT: A staged as hi+lo bf16 (near-fp32 A precision).
// MODE 0: store fp32 C (opt bias/act). MODE 1: store bf16 Cb.
// MODE 2: attention epilogue: sim[row] = sum_a tanh(C[row][a]+batt[a])*q[a];
//         blockIdx.y = k selects A/Bt/bias/q/sim slice.
#define LDSP 40   // LDS row stride in u16 (32 + 8 pad)
template<int BN_, int MODE, bool SPLIT, bool BIAS, int ACT>
__global__ __launch_bounds__(256) void gemm_mfma(
        const float* __restrict__ A, const u16* __restrict__ Bt,
        const float* __restrict__ bias, const float* __restrict__ qv,
        float* __restrict__ Cf, u16* __restrict__ Cb,
        float* __restrict__ simp, int M, int Kd, int Nc) {
    constexpr int JW = BN_ / 32;           // j-frags per wave
    __shared__ u16 AsHi[128 * LDSP];
    __shared__ u16 AsLo[SPLIT ? 128 * LDSP : 1];
    __shared__ u16 Bs[BN_ * LDSP];
    __shared__ float simbuf[4][64];

    const int tid = threadIdx.x;
    const int lane = tid & 63, waveid = tid >> 6;
    const int wy = waveid >> 1, wx = waveid & 1;
    const int lane15 = lane & 15, quad = lane >> 4;
    const int bm = blockIdx.x * 128;
    int bn = 0;
    if constexpr (MODE != 2) bn = blockIdx.y * BN_;
    if constexpr (MODE == 2) {
        size_t kk = blockIdx.y;
        A    += kk * ((size_t)NN * DD);
        Bt   += kk * (size_t)ATTD * Kd;
        bias += kk * ATTD;
        qv   += kk * ATTD;
        simp += kk * NN;
    }

    floatx4 acc[4][JW];
#pragma unroll
    for (int i = 0; i < 4; ++i)
#pragma unroll
        for (int j = 0; j < JW; ++j) acc[i][j] = (floatx4){0.f, 0.f, 0.f, 0.f};

    for (int k0 = 0; k0 < Kd; k0 += 32) {
        // ---- stage A (fp32 -> bf16 hi/lo) ----
#pragma unroll
        for (int t = tid; t < 1024; t += 256) {
            int m = t >> 3, k4 = (t & 7) << 2;
            float4 v = make_float4(0.f, 0.f, 0.f, 0.f);
            if (bm + m < M) v = *(const float4*)(A + (size_t)(bm + m) * Kd + k0 + k4);
            u16 h0 = f2bf(v.x), h1 = f2bf(v.y), h2 = f2bf(v.z), h3 = f2bf(v.w);
            *(ushort4*)(void*)(AsHi + m * LDSP + k4) = make_ushort4(h0, h1, h2, h3);
            if constexpr (SPLIT) {
                u16 l0 = f2bf(v.x - bf2f(h0)), l1 = f2bf(v.y - bf2f(h1));
                u16 l2 = f2bf(v.z - bf2f(h2)), l3 = f2bf(v.w - bf2f(h3));
                *(ushort4*)(void*)(AsLo + m * LDSP + k4) = make_ushort4(l0, l1, l2, l3);
            }
        }
        // ---- stage B (already bf16, [n][k]) ----
#pragma unroll
        for (int t = tid; t < BN_ * 4; t += 256) {
            int n = t >> 2, ko = (t & 3) << 3;
            uint4 w = *(const uint4*)(Bt + (size_t)(bn + n) * Kd + k0 + ko);
            *(uint4*)(void*)(Bs + n * LDSP + ko) = w;
        }
        __syncthreads();

        const u16* pA  = AsHi + (wy * 64 + lane15) * LDSP + quad * 8;
        const u16* pAl = AsLo + (wy * 64 + lane15) * LDSP + quad * 8;
        const u16* pB  = Bs + (wx * (BN_ / 2) + lane15) * LDSP + quad * 8;
        short8 b[JW];
#pragma unroll
        for (int j = 0; j < JW; ++j) b[j] = *(const short8*)(pB + j * 16 * LDSP);
#pragma unroll
        for (int i = 0; i < 4; ++i) {
            short8 a = *(const short8*)(pA + i * 16 * LDSP);
#pragma unroll
            for (int j = 0; j < JW; ++j)
                acc[i][j] = __builtin_amdgcn_mfma_f32_16x16x32_bf16(a, b[j], acc[i][j], 0, 0, 0);
        }
        if constexpr (SPLIT) {
#pragma unroll
            for (int i = 0; i < 4; ++i) {
                short8 a = *(const short8*)(pAl + i * 16 * LDSP);
#pragma unroll
                for (int j = 0; j < JW; ++j)
                    acc[i][j] = __builtin_amdgcn_mfma_f32_16x16x32_bf16(a, b[j], acc[i][j], 0, 0, 0);
            }
        }
        __syncthreads();
    }

    if constexpr (MODE == 2) {
        // epilogue: sim[row] = sum_col tanh(v + batt[col]) * q[col]
#pragma unroll
        for (int i = 0; i < 4; ++i) {
#pragma unroll
            for (int r = 0; r < 4; ++r) {
                float p = 0.f;
#pragma unroll
                for (int j = 0; j < JW; ++j) {
                    int col = wx * 32 + j * 16 + lane15;
                    float v = acc[i][j][r] + bias[col];
                    p += tanhf(v) * qv[col];
                }
                p += __shfl_xor(p, 1, 64);
                p += __shfl_xor(p, 2, 64);
                p += __shfl_xor(p, 4, 64);
                p += __shfl_xor(p, 8, 64);
                if (lane15 == 0) simbuf[wy * 2 + wx][i * 16 + quad * 4 + r] = p;
            }
        }
        __syncthreads();
        if (tid < 128) {
            int wyy = tid >> 6, rl = tid & 63;
            int row = bm + wyy * 64 + rl;
            if (row < M) simp[row] = simbuf[wyy * 2 + 0][rl] + simbuf[wyy * 2 + 1][rl];
        }
    } else {
#pragma unroll
        for (int i = 0; i < 4; ++i) {
#pragma unroll
            for (int r = 0; r < 4; ++r) {
                int row = bm + wy * 64 + i * 16 + quad * 4 + r;
                if (row >= M) continue;
#pragma unroll
                for (int j = 0; j < JW; ++j) {
                    int col = bn + wx * (BN_ / 2) + j * 16 + lane15;
                    float v = acc[i][j][r];
                    if constexpr (BIAS) v += bias[col];
                    if constexpr (ACT == 1) v = v > 0.f ? v : SLOPE * v;
                    if constexpr (MODE == 0) Cf[(size_t)row * Nc + col] = v;
                    else                     Cb[(size_t)row * Nc + col] = f2bf(v);
                }
            }
        }
    }
}

// ---------------- softmax over K=2 + combine + relu ----------------
__global__ void combine_relu(const float* __restrict__ xs, const float* __restrict__ sim,
                             const float* __restrict__ gcnb, float* __restrict__ h) {
    size_t i = (size_t)blockIdx.x * blockDim.x + threadIdx.x;
    int n = (int)(i >> 6);
    int dq = (int)(i & 63);
    float s0 = sim[n], s1 = sim[NN + n];
    float m = fmaxf(s0, s1);
    float e0 = expf(s0 - m), e1 = expf(s1 - m);
    float inv = 1.f / (e0 + e1);
    float a0 = e0 * inv, a1 = e1 * inv;
    float4 v0 = ((const float4*)xs)[i];
    float4 v1 = ((const float4*)(xs + (size_t)NN * DD))[i];
    float4 bv = ((const float4*)gcnb)[dq];
    float4 r;
    r.x = fmaxf(0.f, a0 * v0.x + a1 * v1.x + bv.x);
    r.y = fmaxf(0.f, a0 * v0.y + a1 * v1.y + bv.y);
    r.z = fmaxf(0.f, a0 * v0.z + a1 * v1.z + bv.z);
    r.w = fmaxf(0.f, a0 * v0.w + a1 * v1.w + bv.w);
    ((float4*)h)[i] = r;
}

extern "C" void kernel_launch(void* const* d_in, const int* in_sizes, int n_in,
                              void* d_out, int out_size, void* d_ws, size_t ws_size,
                              hipStream_t stream) {
    const float* x     = (const float*)d_in[0];
    const int*   ei    = (const int*)d_in[1];
    const float* ew    = (const float*)d_in[2];
    const float* gamma = (const float*)d_in[3];
    const float* beta  = (const float*)d_in[4];
    const float* gcn_W = (const float*)d_in[5];
    const float* gcn_b = (const float*)d_in[6];
    const float* att_W = (const float*)d_in[7];
    const float* att_b = (const float*)d_in[8];
    const float* att_q = (const float*)d_in[9];
    const float* pW1   = (const float*)d_in[10];
    const float* pb1   = (const float*)d_in[11];
    const float* pW2   = (const float*)d_in[12];
    const float* pb2   = (const float*)d_in[13];
    float* out = (float*)d_out;

    char* wsb = (char*)d_ws;
    size_t off = 0;
    auto alloc = [&](size_t bytes) -> void* {
        void* p = wsb + off;
        off += (bytes + 255) & ~(size_t)255;
        return p;
    };
    float* xs    = (float*)alloc((size_t)KD * NN * DD * 4);   // 204.8 MB
    float* h     = xs;                                        // alias xs[k=0]
    u16*   xw    = (u16*)alloc((size_t)NN * DD * 2);          // 51.2 MB
    float* p1tmp = (float*)xw;                                // N*H1*4, exact reuse
    float* dinv  = (float*)alloc((size_t)KN * 4);
    float* sim   = (float*)alloc((size_t)KN * 4);
    int*   starts= (int*)alloc(((size_t)KN + 1) * 4);
    int2*  edata = (int2*)alloc((size_t)KD * EE * 8);         // 6.4 MB
    float* bnsums= (float*)alloc(2 * DD * 4);
    u16*   gcnWb = (u16*)alloc((size_t)LL * DD * DD * 2);     // 393 KB
    u16*   attWb = (u16*)alloc((size_t)LL * KD * ATTD * DD * 2); // 196 KB
    u16*   pW1b  = (u16*)alloc((size_t)HH1 * DD * 2);
    u16*   pW2b  = (u16*)alloc((size_t)HH2 * HH1 * 2);
    float* batt  = (float*)alloc((size_t)LL * KD * ATTD * 4);

    // ---- setup: weight transpose/convert + att bias fold ----
    for (int l = 0; l < LL; ++l)
        wconv<<<(DD * DD + 255) / 256, 256, 0, stream>>>(gcn_W + (size_t)l * DD * DD,
                                                         gcnWb + (size_t)l * DD * DD, DD, DD);
    for (int lk = 0; lk < LL * KD; ++lk)
        wconv<<<(DD * ATTD + 255) / 256, 256, 0, stream>>>(att_W + (size_t)lk * DD * ATTD,
                                                           attWb + (size_t)lk * ATTD * DD, DD, ATTD);
    wconv<<<(DD * HH1 + 255) / 256, 256, 0, stream>>>(pW1, pW1b, DD, HH1);
    wconv<<<(HH1 * HH2 + 255) / 256, 256, 0, stream>>>(pW2, pW2b, HH1, HH2);
    att_bias_fold<<<LL * KD, ATTD, 0, stream>>>(att_W, att_b, gcn_b, batt);

    // ---- BatchNorm -> h ----
    hipMemsetAsync(bnsums, 0, 2 * DD * 4, stream);
    bn_stats<<<800, 256, 0, stream>>>(x, bnsums);
    bn_apply<<<25000, 256, 0, stream>>>(x, bnsums, gamma, beta, h);

    // ---- degree / dinv / CSR (layer-invariant) ----
    hipMemsetAsync(dinv, 0, (size_t)KN * 4, stream);
    deg_accum<<<(KD * EE + 255) / 256, 256, 0, stream>>>(ei, ew, dinv);
    dinv_kernel<<<(KN + 255) / 256, 256, 0, stream>>>(dinv);
    hipMemsetAsync(starts, 0, ((size_t)KN + 1) * 4, stream);
    csr_count<<<(KD * EE + 255) / 256, 256, 0, stream>>>(ei, starts);
    csr_scan<<<1, 256, 0, stream>>>(starts);
    csr_fill<<<(KD * EE + 255) / 256, 256, 0, stream>>>(ei, ew, dinv, starts, edata);

    const int MB = (NN + 127) / 128;   // 782
    for (int l = 0; l < LL; ++l) {
        // xw(bf16) = h @ gcn_W[l]  (split-A MFMA)
        gemm_mfma<128, 1, true, false, 0><<<dim3(MB, DD / 128), 256, 0, stream>>>(
            h, gcnWb + (size_t)l * DD * DD, nullptr, nullptr,
            nullptr, xw, nullptr, NN, DD, DD);
        gather_agg<<<(KN + 3) / 4, 256, 0, stream>>>(starts, edata,
                                                     (const __hip_bfloat16*)xw, xs);
        // fused keys/tanh/sim (single-bf16 MFMA, epilogue reduce)
        gemm_mfma<64, 2, false, false, 0><<<dim3(MB, KD), 256, 0, stream>>>(
            xs, attWb + (size_t)l * KD * ATTD * DD,
            batt + (size_t)l * KD * ATTD, att_q + (size_t)l * KD * ATTD,
            nullptr, nullptr, sim, NN, DD, ATTD);
        combine_relu<<<25000, 256, 0, stream>>>(xs, sim, gcn_b + l * DD, h);
    }

    // ---- projection head ----
    gemm_mfma<128, 0, true, true, 1><<<dim3(MB, 1), 256, 0, stream>>>(
        h, pW1b, pb1, nullptr, p1tmp, nullptr, nullptr, NN, DD, HH1);
    gemm_mfma<64, 0, true, true, 1><<<dim3(MB, 1), 256, 0, stream>>>(
        p1tmp, pW2b, pb2, nullptr, out, nullptr, nullptr, NN, HH1, HH2);
}

// Round 5
// 1318.613 us; speedup vs baseline: 8.9527x; 1.3138x over previous
//
#include <hip/hip_runtime.h>
#include <hip/hip_bf16.h>
#include <math.h>

#define NN 100000
#define EE 400000
#define KD 2
#define DD 256
#define ATTD 64
#define LL 3
#define HH1 128
#define HH2 64
#define EPSV 1e-5f
#define SLOPE 0.01f
#define KN (KD * NN)

typedef short short8 __attribute__((ext_vector_type(8)));
typedef float floatx4 __attribute__((ext_vector_type(4)));
typedef unsigned short u16;
typedef unsigned int u32;

__device__ __forceinline__ u16 f2bf(float f) {
    u32 u = __float_as_uint(f);
    return (u16)((u + 0x7fffu + ((u >> 16) & 1u)) >> 16);
}
__device__ __forceinline__ float bf2f(u16 h) {
    return __uint_as_float((u32)h << 16);
}

// ---------------- BatchNorm ----------------
__global__ void bn_stats(const float* __restrict__ x, float* __restrict__ sums) {
    int d = threadIdx.x;
    int r0 = blockIdx.x * 125;
    float s = 0.f, sq = 0.f;
    for (int r = r0; r < r0 + 125; ++r) {
        float v = x[(size_t)r * DD + d];
        s += v; sq += v * v;
    }
    atomicAdd(&sums[d], s);
    atomicAdd(&sums[DD + d], sq);
}

__global__ void bn_apply(const float* __restrict__ x, const float* __restrict__ sums,
                         const float* __restrict__ gamma, const float* __restrict__ beta,
                         float* __restrict__ h) {
    size_t i = (size_t)blockIdx.x * blockDim.x + threadIdx.x;
    const float inv_n = 1.f / NN;
    int dq = (int)(i & 63) * 4;
    float4 xv = ((const float4*)x)[i];
    float4 hv;
    float* xp = (float*)&xv; float* hp = (float*)&hv;
#pragma unroll
    for (int j = 0; j < 4; ++j) {
        int d = dq + j;
        float mu = sums[d] * inv_n;
        float var = sums[DD + d] * inv_n - mu * mu;
        float inv = rsqrtf(var + EPSV);
        hp[j] = (xp[j] - mu) * inv * gamma[d] + beta[d];
    }
    ((float4*)h)[i] = hv;
}

// ---------------- degree ----------------
__global__ void deg_accum(const int* __restrict__ ei, const float* __restrict__ w,
                          float* __restrict__ deg) {
    int i = blockIdx.x * blockDim.x + threadIdx.x;
    if (i >= KD * EE) return;
    int k = i / EE, e = i - k * EE;
    int col = ei[(size_t)k * 2 * EE + EE + e];
    atomicAdd(&deg[k * NN + col], w[i]);
}

__global__ void dinv_kernel(float* __restrict__ d) {
    int i = blockIdx.x * blockDim.x + threadIdx.x;
    if (i >= KD * NN) return;
    float v = d[i];
    d[i] = v > 0.f ? 1.f / sqrtf(v) : 0.f;
}

// ---------------- CSR build ----------------
__global__ void csr_count(const int* __restrict__ ei, int* __restrict__ starts) {
    int i = blockIdx.x * blockDim.x + threadIdx.x;
    if (i >= KD * EE) return;
    int k = i / EE, e = i - k * EE;
    int col = ei[(size_t)k * 2 * EE + EE + e];
    atomicAdd(&starts[k * NN + col], 1);
}

// ---- parallel hierarchical exclusive scan over starts[0..KN) ----
#define SCAN_NB ((KN + 255) / 256)   // 782
__global__ void scan_blocks(int* __restrict__ starts, int* __restrict__ bsums) {
    __shared__ int tmp[256];
    int t = threadIdx.x;
    int idx = blockIdx.x * 256 + t;
    int v = (idx < KN) ? starts[idx] : 0;
    tmp[t] = v;
    __syncthreads();
#pragma unroll
    for (int off = 1; off < 256; off <<= 1) {
        int s = (t >= off) ? tmp[t - off] : 0;
        __syncthreads();
        tmp[t] += s;
        __syncthreads();
    }
    if (idx < KN) starts[idx] = tmp[t] - v;          // exclusive
    if (t == 255) bsums[blockIdx.x] = tmp[255];      // block total
}

__global__ void scan_sums(int* __restrict__ bsums) {
    __shared__ int tmp[1024];
    int t = threadIdx.x;
    int v = (t < SCAN_NB) ? bsums[t] : 0;
    tmp[t] = v;
    __syncthreads();
#pragma unroll
    for (int off = 1; off < 1024; off <<= 1) {
        int s = (t >= off) ? tmp[t - off] : 0;
        __syncthreads();
        tmp[t] += s;
        __syncthreads();
    }
    if (t < SCAN_NB) bsums[t] = tmp[t] - v;          // exclusive
}

__global__ void scan_add(int* __restrict__ starts, const int* __restrict__ bsums) {
    int idx = blockIdx.x * 256 + threadIdx.x;
    if (idx < KN) starts[idx] += bsums[blockIdx.x];
}

__global__ void csr_fill(const int* __restrict__ ei, const float* __restrict__ w,
                         const float* __restrict__ dinv,
                         int* __restrict__ starts, int2* __restrict__ edata) {
    int i = blockIdx.x * blockDim.x + threadIdx.x;
    if (i >= KD * EE) return;
    int k = i / EE, e = i - k * EE;
    const int* eik = ei + (size_t)k * 2 * EE;
    int row = eik[e], col = eik[EE + e];
    float nv = dinv[k * NN + col] * w[i] * dinv[k * NN + row];
    int pos = atomicAdd(&starts[k * NN + col], 1);
    edata[pos] = make_int2(row, __float_as_int(nv));
}

// ---------------- gather aggregation ----------------
__global__ __launch_bounds__(256) void gather_agg(
        const int* __restrict__ starts, const int2* __restrict__ edata,
        const __hip_bfloat16* __restrict__ xw, float* __restrict__ xs) {
    int widx = blockIdx.x * 4 + (threadIdx.x >> 6);
    if (widx >= KN) return;
    int lane = threadIdx.x & 63;
    int begin = widx ? starts[widx - 1] : 0;
    int end = starts[widx];
    float4 acc = make_float4(0.f, 0.f, 0.f, 0.f);
    for (int e = begin; e < end; ++e) {
        int2 ed = edata[e];
        float nv = __int_as_float(ed.y);
        const __hip_bfloat162* p =
            (const __hip_bfloat162*)(xw + (size_t)ed.x * DD + lane * 4);
        float2 f0 = __bfloat1622float2(p[0]);
        float2 f1 = __bfloat1622float2(p[1]);
        acc.x += nv * f0.x; acc.y += nv * f0.y;
        acc.z += nv * f1.x; acc.w += nv * f1.y;
    }
    ((float4*)(xs + (size_t)widx * DD))[lane] = acc;
}

// ---------------- weight convert + transpose: Wt[n][k] = bf16(W[k][n]) ----------------
__global__ void wconv(const float* __restrict__ W, u16* __restrict__ Wt, int Kd, int Nc) {
    int i = blockIdx.x * 256 + threadIdx.x;
    if (i >= Kd * Nc) return;
    int kk = i / Nc, n = i - kk * Nc;
    Wt[(size_t)n * Kd + kk] = f2bf(W[i]);
}

// ---------------- fold gcn_b into attention bias ----------------
__global__ void att_bias_fold(const float* __restrict__ attW, const float* __restrict__ attb,
                              const float* __restrict__ gcnb, float* __restrict__ batt) {
    int lk = blockIdx.x;          // 0..5
    int a = threadIdx.x;          // 0..63
    int l = lk >> 1;
    const float* W = attW + (size_t)lk * DD * ATTD;
    const float* gb = gcnb + l * DD;
    float s = attb[lk * ATTD + a];
    for (int d = 0; d < DD; ++d) s += gb[d] * W[d * ATTD + a];
    batt[lk * ATTD + a] = s;
}

// ---------------- MFMA GEMM ----------------
#define LDSP 40   // LDS row stride in u16 (32 + 8 pad)
template<int BN_, int MODE, bool SPLIT, bool BIAS, int ACT>
__global__ __launch_bounds__(256) void gemm_mfma(
        const float* __restrict__ A, const u16* __restrict__ Bt,
        const float* __restrict__ bias, const float* __restrict__ qv,
        float* __restrict__ Cf, u16* __restrict__ Cb,
        float* __restrict__ simp, int M, int Kd, int Nc) {
    constexpr int JW = BN_ / 32;           // j-frags per wave
    __shared__ u16 AsHi[128 * LDSP];
    __shared__ u16 AsLo[SPLIT ? 128 * LDSP : 1];
    __shared__ u16 Bs[BN_ * LDSP];
    __shared__ float simbuf[4][64];

    const int tid = threadIdx.x;
    const int lane = tid & 63, waveid = tid >> 6;
    const int wy = waveid >> 1, wx = waveid & 1;
    const int lane15 = lane & 15, quad = lane >> 4;
    const int bm = blockIdx.x * 128;
    int bn = 0;
    if constexpr (MODE != 2) bn = blockIdx.y * BN_;
    if constexpr (MODE == 2) {
        size_t kk = blockIdx.y;
        A    += kk * ((size_t)NN * DD);
        Bt   += kk * (size_t)ATTD * Kd;
        bias += kk * ATTD;
        qv   += kk * ATTD;
        simp += kk * NN;
    }

    floatx4 acc[4][JW];
#pragma unroll
    for (int i = 0; i < 4; ++i)
#pragma unroll
        for (int j = 0; j < JW; ++j) acc[i][j] = (floatx4){0.f, 0.f, 0.f, 0.f};

    for (int k0 = 0; k0 < Kd; k0 += 32) {
        // ---- stage A (fp32 -> bf16 hi/lo) ----
#pragma unroll
        for (int t = tid; t < 1024; t += 256) {
            int m = t >> 3, k4 = (t & 7) << 2;
            float4 v = make_float4(0.f, 0.f, 0.f, 0.f);
            if (bm + m < M) v = *(const float4*)(A + (size_t)(bm + m) * Kd + k0 + k4);
            u16 h0 = f2bf(v.x), h1 = f2bf(v.y), h2 = f2bf(v.z), h3 = f2bf(v.w);
            *(ushort4*)(void*)(AsHi + m * LDSP + k4) = make_ushort4(h0, h1, h2, h3);
            if constexpr (SPLIT) {
                u16 l0 = f2bf(v.x - bf2f(h0)), l1 = f2bf(v.y - bf2f(h1));
                u16 l2 = f2bf(v.z - bf2f(h2)), l3 = f2bf(v.w - bf2f(h3));
                *(ushort4*)(void*)(AsLo + m * LDSP + k4) = make_ushort4(l0, l1, l2, l3);
            }
        }
        // ---- stage B (already bf16, [n][k]) ----
#pragma unroll
        for (int t = tid; t < BN_ * 4; t += 256) {
            int n = t >> 2, ko = (t & 3) << 3;
            uint4 w = *(const uint4*)(Bt + (size_t)(bn + n) * Kd + k0 + ko);
            *(uint4*)(void*)(Bs + n * LDSP + ko) = w;
        }
        __syncthreads();

        const u16* pA  = AsHi + (wy * 64 + lane15) * LDSP + quad * 8;
        const u16* pAl = AsLo + (wy * 64 + lane15) * LDSP + quad * 8;
        const u16* pB  = Bs + (wx * (BN_ / 2) + lane15) * LDSP + quad * 8;
        short8 b[JW];
#pragma unroll
        for (int j = 0; j < JW; ++j) b[j] = *(const short8*)(pB + j * 16 * LDSP);
#pragma unroll
        for (int i = 0; i < 4; ++i) {
            short8 a = *(const short8*)(pA + i * 16 * LDSP);
#pragma unroll
            for (int j = 0; j < JW; ++j)
                acc[i][j] = __builtin_amdgcn_mfma_f32_16x16x32_bf16(a, b[j], acc[i][j], 0, 0, 0);
        }
        if constexpr (SPLIT) {
#pragma unroll
            for (int i = 0; i < 4; ++i) {
                short8 a = *(const short8*)(pAl + i * 16 * LDSP);
#pragma unroll
                for (int j = 0; j < JW; ++j)
                    acc[i][j] = __builtin_amdgcn_mfma_f32_16x16x32_bf16(a, b[j], acc[i][j], 0, 0, 0);
            }
        }
        __syncthreads();
    }

    if constexpr (MODE == 2) {
        // epilogue: sim[row] = sum_col tanh(v + batt[col]) * q[col]
#pragma unroll
        for (int i = 0; i < 4; ++i) {
#pragma unroll
            for (int r = 0; r < 4; ++r) {
                float p = 0.f;
#pragma unroll
                for (int j = 0; j < JW; ++j) {
                    int col = wx * 32 + j * 16 + lane15;
                    float v = acc[i][j][r] + bias[col];
                    p += tanhf(v) * qv[col];
                }
                p += __shfl_xor(p, 1, 64);
                p += __shfl_xor(p, 2, 64);
                p += __shfl_xor(p, 4, 64);
                p += __shfl_xor(p, 8, 64);
                if (lane15 == 0) simbuf[wy * 2 + wx][i * 16 + quad * 4 + r] = p;
            }
        }
        __syncthreads();
        if (tid < 128) {
            int wyy = tid >> 6, rl = tid & 63;
            int row = bm + wyy * 64 + rl;
            if (row < M) simp[row] = simbuf[wyy * 2 + 0][rl] + simbuf[wyy * 2 + 1][rl];
        }
    } else {
#pragma unroll
        for (int i = 0; i < 4; ++i) {
#pragma unroll
            for (int r = 0; r < 4; ++r) {
                int row = bm + wy * 64 + i * 16 + quad * 4 + r;
                if (row >= M) continue;
#pragma unroll
                for (int j = 0; j < JW; ++j) {
                    int col = bn + wx * (BN_ / 2) + j * 16 + lane15;
                    float v = acc[i][j][r];
                    if constexpr (BIAS) v += bias[col];
                    if constexpr (ACT == 1) v = v > 0.f ? v : SLOPE * v;
                    if constexpr (MODE == 0) Cf[(size_t)row * Nc + col] = v;
                    else                     Cb[(size_t)row * Nc + col] = f2bf(v);
                }
            }
        }
    }
}

// ---------------- softmax over K=2 + combine + relu ----------------
__global__ void combine_relu(const float* __restrict__ xs, const float* __restrict__ sim,
                             const float* __restrict__ gcnb, float* __restrict__ h) {
    size_t i = (size_t)blockIdx.x * blockDim.x + threadIdx.x;
    int n = (int)(i >> 6);
    int dq = (int)(i & 63);
    float s0 = sim[n], s1 = sim[NN + n];
    float m = fmaxf(s0, s1);
    float e0 = expf(s0 - m), e1 = expf(s1 - m);
    float inv = 1.f / (e0 + e1);
    float a0 = e0 * inv, a1 = e1 * inv;
    float4 v0 = ((const float4*)xs)[i];
    float4 v1 = ((const float4*)(xs + (size_t)NN * DD))[i];
    float4 bv = ((const float4*)gcnb)[dq];
    float4 r;
    r.x = fmaxf(0.f, a0 * v0.x + a1 * v1.x + bv.x);
    r.y = fmaxf(0.f, a0 * v0.y + a1 * v1.y + bv.y);
    r.z = fmaxf(0.f, a0 * v0.z + a1 * v1.z + bv.z);
    r.w = fmaxf(0.f, a0 * v0.w + a1 * v1.w + bv.w);
    ((float4*)h)[i] = r;
}

extern "C" void kernel_launch(void* const* d_in, const int* in_sizes, int n_in,
                              void* d_out, int out_size, void* d_ws, size_t ws_size,
                              hipStream_t stream) {
    const float* x     = (const float*)d_in[0];
    const int*   ei    = (const int*)d_in[1];
    const float* ew    = (const float*)d_in[2];
    const float* gamma = (const float*)d_in[3];
    const float* beta  = (const float*)d_in[4];
    const float* gcn_W = (const float*)d_in[5];
    const float* gcn_b = (const float*)d_in[6];
    const float* att_W = (const float*)d_in[7];
    const float* att_b = (const float*)d_in[8];
    const float* att_q = (const float*)d_in[9];
    const float* pW1   = (const float*)d_in[10];
    const float* pb1   = (const float*)d_in[11];
    const float* pW2   = (const float*)d_in[12];
    const float* pb2   = (const float*)d_in[13];
    float* out = (float*)d_out;

    char* wsb = (char*)d_ws;
    size_t off = 0;
    auto alloc = [&](size_t bytes) -> void* {
        void* p = wsb + off;
        off += (bytes + 255) & ~(size_t)255;
        return p;
    };
    float* xs    = (float*)alloc((size_t)KD * NN * DD * 4);   // 204.8 MB
    float* h     = xs;                                        // alias xs[k=0]
    u16*   xw    = (u16*)alloc((size_t)NN * DD * 2);          // 51.2 MB
    float* p1tmp = (float*)xw;                                // N*H1*4, exact reuse
    float* dinv  = (float*)alloc((size_t)KN * 4);
    float* sim   = (float*)alloc((size_t)KN * 4);
    int*   starts= (int*)alloc(((size_t)KN + 1) * 4);
    int2*  edata = (int2*)alloc((size_t)KD * EE * 8);         // 6.4 MB
    float* bnsums= (float*)alloc(2 * DD * 4);
    u16*   gcnWb = (u16*)alloc((size_t)LL * DD * DD * 2);     // 393 KB
    u16*   attWb = (u16*)alloc((size_t)LL * KD * ATTD * DD * 2); // 196 KB
    u16*   pW1b  = (u16*)alloc((size_t)HH1 * DD * 2);
    u16*   pW2b  = (u16*)alloc((size_t)HH2 * HH1 * 2);
    float* batt  = (float*)alloc((size_t)LL * KD * ATTD * 4);
    int*   bsums = (int*)alloc((size_t)SCAN_NB * 4);

    // ---- setup: weight transpose/convert + att bias fold ----
    for (int l = 0; l < LL; ++l)
        wconv<<<(DD * DD + 255) / 256, 256, 0, stream>>>(gcn_W + (size_t)l * DD * DD,
                                                         gcnWb + (size_t)l * DD * DD, DD, DD);
    for (int lk = 0; lk < LL * KD; ++lk)
        wconv<<<(DD * ATTD + 255) / 256, 256, 0, stream>>>(att_W + (size_t)lk * DD * ATTD,
                                                           attWb + (size_t)lk * ATTD * DD, DD, ATTD);
    wconv<<<(DD * HH1 + 255) / 256, 256, 0, stream>>>(pW1, pW1b, DD, HH1);
    wconv<<<(HH1 * HH2 + 255) / 256, 256, 0, stream>>>(pW2, pW2b, HH1, HH2);
    att_bias_fold<<<LL * KD, ATTD, 0, stream>>>(att_W, att_b, gcn_b, batt);

    // ---- BatchNorm -> h ----
    hipMemsetAsync(bnsums, 0, 2 * DD * 4, stream);
    bn_stats<<<800, 256, 0, stream>>>(x, bnsums);
    bn_apply<<<25000, 256, 0, stream>>>(x, bnsums, gamma, beta, h);

    // ---- degree / dinv / CSR (layer-invariant) ----
    hipMemsetAsync(dinv, 0, (size_t)KN * 4, stream);
    deg_accum<<<(KD * EE + 255) / 256, 256, 0, stream>>>(ei, ew, dinv);
    dinv_kernel<<<(KN + 255) / 256, 256, 0, stream>>>(dinv);
    hipMemsetAsync(starts, 0, ((size_t)KN + 1) * 4, stream);
    csr_count<<<(KD * EE + 255) / 256, 256, 0, stream>>>(ei, starts);
    scan_blocks<<<SCAN_NB, 256, 0, stream>>>(starts, bsums);
    scan_sums<<<1, 1024, 0, stream>>>(bsums);
    scan_add<<<SCAN_NB, 256, 0, stream>>>(starts, bsums);
    csr_fill<<<(KD * EE + 255) / 256, 256, 0, stream>>>(ei, ew, dinv, starts, edata);

    const int MB = (NN + 127) / 128;   // 782
    for (int l = 0; l < LL; ++l) {
        // xw(bf16) = h @ gcn_W[l]  (split-A MFMA)
        gemm_mfma<128, 1, true, false, 0><<<dim3(MB, DD / 128), 256, 0, stream>>>(
            h, gcnWb + (size_t)l * DD * DD, nullptr, nullptr,
            nullptr, xw, nullptr, NN, DD, DD);
        gather_agg<<<(KN + 3) / 4, 256, 0, stream>>>(starts, edata,
                                                     (const __hip_bfloat16*)xw, xs);
        // fused keys/tanh/sim (single-bf16 MFMA, epilogue reduce)
        gemm_mfma<64, 2, false, false, 0><<<dim3(MB, KD), 256, 0, stream>>>(
            xs, attWb + (size_t)l * KD * ATTD * DD,
            batt + (size_t)l * KD * ATTD, att_q + (size_t)l * KD * ATTD,
            nullptr, nullptr, sim, NN, DD, ATTD);
        combine_relu<<<25000, 256, 0, stream>>>(xs, sim, gcn_b + l * DD, h);
    }

    // ---- projection head ----
    gemm_mfma<128, 0, true, true, 1><<<dim3(MB, 1), 256, 0, stream>>>(
        h, pW1b, pb1, nullptr, p1tmp, nullptr, nullptr, NN, DD, HH1);
    gemm_mfma<64, 0, true, true, 1><<<dim3(MB, 1), 256, 0, stream>>>(
        p1tmp, pW2b, pb2, nullptr, out, nullptr, nullptr, NN, HH1, HH2);
}

// Round 6
// 1284.108 us; speedup vs baseline: 9.1932x; 1.0269x over previous
//
#include <hip/hip_runtime.h>
#include <hip/hip_bf16.h>
#include <math.h>

#define NN 100000
#define EE 400000
#define KD 2
#define DD 256
#define ATTD 64
#define LL 3
#define HH1 128
#define HH2 64
#define EPSV 1e-5f
#define SLOPE 0.01f
#define KN (KD * NN)

typedef short short8 __attribute__((ext_vector_type(8)));
typedef float floatx4 __attribute__((ext_vector_type(4)));
typedef unsigned short u16;
typedef unsigned int u32;

__device__ __forceinline__ u16 f2bf(float f) {
    u32 u = __float_as_uint(f);
    return (u16)((u + 0x7fffu + ((u >> 16) & 1u)) >> 16);
}
__device__ __forceinline__ float bf2f(u16 h) {
    return __uint_as_float((u32)h << 16);
}

// ---------------- BatchNorm ----------------
__global__ void bn_stats(const float* __restrict__ x, float* __restrict__ sums) {
    int d = threadIdx.x;
    int r0 = blockIdx.x * 125;
    float s = 0.f, sq = 0.f;
    for (int r = r0; r < r0 + 125; ++r) {
        float v = x[(size_t)r * DD + d];
        s += v; sq += v * v;
    }
    atomicAdd(&sums[d], s);
    atomicAdd(&sums[DD + d], sq);
}

__global__ void bn_apply(const float* __restrict__ x, const float* __restrict__ sums,
                         const float* __restrict__ gamma, const float* __restrict__ beta,
                         float* __restrict__ h) {
    size_t i = (size_t)blockIdx.x * blockDim.x + threadIdx.x;
    const float inv_n = 1.f / NN;
    int dq = (int)(i & 63) * 4;
    float4 xv = ((const float4*)x)[i];
    float4 hv;
    float* xp = (float*)&xv; float* hp = (float*)&hv;
#pragma unroll
    for (int j = 0; j < 4; ++j) {
        int d = dq + j;
        float mu = sums[d] * inv_n;
        float var = sums[DD + d] * inv_n - mu * mu;
        float inv = rsqrtf(var + EPSV);
        hp[j] = (xp[j] - mu) * inv * gamma[d] + beta[d];
    }
    ((float4*)h)[i] = hv;
}

// ---------------- degree ----------------
__global__ void deg_accum(const int* __restrict__ ei, const float* __restrict__ w,
                          float* __restrict__ deg) {
    int i = blockIdx.x * blockDim.x + threadIdx.x;
    if (i >= KD * EE) return;
    int k = i / EE, e = i - k * EE;
    int col = ei[(size_t)k * 2 * EE + EE + e];
    atomicAdd(&deg[k * NN + col], w[i]);
}

__global__ void dinv_kernel(float* __restrict__ d) {
    int i = blockIdx.x * blockDim.x + threadIdx.x;
    if (i >= KD * NN) return;
    float v = d[i];
    d[i] = v > 0.f ? 1.f / sqrtf(v) : 0.f;
}

// ---------------- CSR build ----------------
__global__ void csr_count(const int* __restrict__ ei, int* __restrict__ starts) {
    int i = blockIdx.x * blockDim.x + threadIdx.x;
    if (i >= KD * EE) return;
    int k = i / EE, e = i - k * EE;
    int col = ei[(size_t)k * 2 * EE + EE + e];
    atomicAdd(&starts[k * NN + col], 1);
}

#define SCAN_NB ((KN + 255) / 256)   // 782
__global__ void scan_blocks(int* __restrict__ starts, int* __restrict__ bsums) {
    __shared__ int tmp[256];
    int t = threadIdx.x;
    int idx = blockIdx.x * 256 + t;
    int v = (idx < KN) ? starts[idx] : 0;
    tmp[t] = v;
    __syncthreads();
#pragma unroll
    for (int off = 1; off < 256; off <<= 1) {
        int s = (t >= off) ? tmp[t - off] : 0;
        __syncthreads();
        tmp[t] += s;
        __syncthreads();
    }
    if (idx < KN) starts[idx] = tmp[t] - v;          // exclusive
    if (t == 255) bsums[blockIdx.x] = tmp[255];      // block total
}

__global__ void scan_sums(int* __restrict__ bsums) {
    __shared__ int tmp[1024];
    int t = threadIdx.x;
    int v = (t < SCAN_NB) ? bsums[t] : 0;
    tmp[t] = v;
    __syncthreads();
#pragma unroll
    for (int off = 1; off < 1024; off <<= 1) {
        int s = (t >= off) ? tmp[t - off] : 0;
        __syncthreads();
        tmp[t] += s;
        __syncthreads();
    }
    if (t < SCAN_NB) bsums[t] = tmp[t] - v;          // exclusive
}

__global__ void scan_add(int* __restrict__ starts, const int* __restrict__ bsums) {
    int idx = blockIdx.x * 256 + threadIdx.x;
    if (idx < KN) starts[idx] += bsums[blockIdx.x];
}

__global__ void csr_fill(const int* __restrict__ ei, const float* __restrict__ w,
                         const float* __restrict__ dinv,
                         int* __restrict__ starts, int2* __restrict__ edata) {
    int i = blockIdx.x * blockDim.x + threadIdx.x;
    if (i >= KD * EE) return;
    int k = i / EE, e = i - k * EE;
    const int* eik = ei + (size_t)k * 2 * EE;
    int row = eik[e], col = eik[EE + e];
    float nv = dinv[k * NN + col] * w[i] * dinv[k * NN + row];
    int pos = atomicAdd(&starts[k * NN + col], 1);
    edata[pos] = make_int2(row, __float_as_int(nv));
}

// ---------------- gather aggregation: xs(bf16)[widx,:] = sum_e norm_e * xw[row_e,:] ----------------
__global__ __launch_bounds__(256) void gather_agg(
        const int* __restrict__ starts, const int2* __restrict__ edata,
        const __hip_bfloat16* __restrict__ xw, u16* __restrict__ xs) {
    int widx = blockIdx.x * 4 + (threadIdx.x >> 6);
    if (widx >= KN) return;
    int lane = threadIdx.x & 63;
    int begin = widx ? starts[widx - 1] : 0;
    int end = starts[widx];
    float4 acc = make_float4(0.f, 0.f, 0.f, 0.f);
    for (int e = begin; e < end; ++e) {
        int2 ed = edata[e];
        float nv = __int_as_float(ed.y);
        const __hip_bfloat162* p =
            (const __hip_bfloat162*)(xw + (size_t)ed.x * DD + lane * 4);
        float2 f0 = __bfloat1622float2(p[0]);
        float2 f1 = __bfloat1622float2(p[1]);
        acc.x += nv * f0.x; acc.y += nv * f0.y;
        acc.z += nv * f1.x; acc.w += nv * f1.y;
    }
    ushort4 st = make_ushort4(f2bf(acc.x), f2bf(acc.y), f2bf(acc.z), f2bf(acc.w));
    *(ushort4*)(xs + (size_t)widx * DD + lane * 4) = st;
}

// ---------------- weight convert + transpose: Wt[n][k] = bf16(W[k][n]) ----------------
__global__ void wconv(const float* __restrict__ W, u16* __restrict__ Wt, int Kd, int Nc) {
    int i = blockIdx.x * 256 + threadIdx.x;
    if (i >= Kd * Nc) return;
    int kk = i / Nc, n = i - kk * Nc;
    Wt[(size_t)n * Kd + kk] = f2bf(W[i]);
}

// ---------------- fold gcn_b into attention bias ----------------
__global__ void att_bias_fold(const float* __restrict__ attW, const float* __restrict__ attb,
                              const float* __restrict__ gcnb, float* __restrict__ batt) {
    int lk = blockIdx.x;          // 0..5
    int a = threadIdx.x;          // 0..63
    int l = lk >> 1;
    const float* W = attW + (size_t)lk * DD * ATTD;
    const float* gb = gcnb + l * DD;
    float s = attb[lk * ATTD + a];
    for (int d = 0; d < DD; ++d) s += gb[d] * W[d * ATTD + a];
    batt[lk * ATTD + a] = s;
}

#define LDSP 40   // LDS row stride in u16 (32 + 8 pad)

// ---------------- MFMA GEMM (fp32 A, split hi/lo staging) ----------------
// MODE 0: store fp32 C (opt bias/act). MODE 1: store bf16 Cb.
template<int BN_, int MODE, bool BIAS, int ACT>
__global__ __launch_bounds__(256) void gemm_mfma(
        const float* __restrict__ A, const u16* __restrict__ Bt,
        const float* __restrict__ bias,
        float* __restrict__ Cf, u16* __restrict__ Cb,
        int M, int Kd, int Nc) {
    constexpr int JW = BN_ / 32;
    __shared__ u16 AsHi[128 * LDSP];
    __shared__ u16 AsLo[128 * LDSP];
    __shared__ u16 Bs[BN_ * LDSP];

    const int tid = threadIdx.x;
    const int lane = tid & 63, waveid = tid >> 6;
    const int wy = waveid >> 1, wx = waveid & 1;
    const int lane15 = lane & 15, quad = lane >> 4;
    const int bm = blockIdx.x * 128;
    const int bn = blockIdx.y * BN_;

    floatx4 acc[4][JW];
#pragma unroll
    for (int i = 0; i < 4; ++i)
#pragma unroll
        for (int j = 0; j < JW; ++j) acc[i][j] = (floatx4){0.f, 0.f, 0.f, 0.f};

    for (int k0 = 0; k0 < Kd; k0 += 32) {
#pragma unroll
        for (int t = tid; t < 1024; t += 256) {
            int m = t >> 3, k4 = (t & 7) << 2;
            float4 v = make_float4(0.f, 0.f, 0.f, 0.f);
            if (bm + m < M) v = *(const float4*)(A + (size_t)(bm + m) * Kd + k0 + k4);
            u16 h0 = f2bf(v.x), h1 = f2bf(v.y), h2 = f2bf(v.z), h3 = f2bf(v.w);
            *(ushort4*)(void*)(AsHi + m * LDSP + k4) = make_ushort4(h0, h1, h2, h3);
            u16 l0 = f2bf(v.x - bf2f(h0)), l1 = f2bf(v.y - bf2f(h1));
            u16 l2 = f2bf(v.z - bf2f(h2)), l3 = f2bf(v.w - bf2f(h3));
            *(ushort4*)(void*)(AsLo + m * LDSP + k4) = make_ushort4(l0, l1, l2, l3);
        }
#pragma unroll
        for (int t = tid; t < BN_ * 4; t += 256) {
            int n = t >> 2, ko = (t & 3) << 3;
            uint4 w = *(const uint4*)(Bt + (size_t)(bn + n) * Kd + k0 + ko);
            *(uint4*)(void*)(Bs + n * LDSP + ko) = w;
        }
        __syncthreads();

        const u16* pA  = AsHi + (wy * 64 + lane15) * LDSP + quad * 8;
        const u16* pAl = AsLo + (wy * 64 + lane15) * LDSP + quad * 8;
        const u16* pB  = Bs + (wx * (BN_ / 2) + lane15) * LDSP + quad * 8;
        short8 b[JW];
#pragma unroll
        for (int j = 0; j < JW; ++j) b[j] = *(const short8*)(pB + j * 16 * LDSP);
#pragma unroll
        for (int i = 0; i < 4; ++i) {
            short8 a = *(const short8*)(pA + i * 16 * LDSP);
#pragma unroll
            for (int j = 0; j < JW; ++j)
                acc[i][j] = __builtin_amdgcn_mfma_f32_16x16x32_bf16(a, b[j], acc[i][j], 0, 0, 0);
        }
#pragma unroll
        for (int i = 0; i < 4; ++i) {
            short8 a = *(const short8*)(pAl + i * 16 * LDSP);
#pragma unroll
            for (int j = 0; j < JW; ++j)
                acc[i][j] = __builtin_amdgcn_mfma_f32_16x16x32_bf16(a, b[j], acc[i][j], 0, 0, 0);
        }
        __syncthreads();
    }

#pragma unroll
    for (int i = 0; i < 4; ++i) {
#pragma unroll
        for (int r = 0; r < 4; ++r) {
            int row = bm + wy * 64 + i * 16 + quad * 4 + r;
            if (row >= M) continue;
#pragma unroll
            for (int j = 0; j < JW; ++j) {
                int col = bn + wx * (BN_ / 2) + j * 16 + lane15;
                float v = acc[i][j][r];
                if constexpr (BIAS) v += bias[col];
                if constexpr (ACT == 1) v = v > 0.f ? v : SLOPE * v;
                if constexpr (MODE == 0) Cf[(size_t)row * Nc + col] = v;
                else                     Cb[(size_t)row * Nc + col] = f2bf(v);
            }
        }
    }
}

// ---------------- fused attention: keys/tanh/sim for BOTH k, softmax, combine, relu ----------------
// xs bf16 (K,N,D). Bt = attWb for this layer, both k: [k][a][d]. batt/q: [k][64].
// Per block: 128 rows. C_k = xs_k @ W_k (128x64 each), sim_k per row, alpha, then
// h[row] = relu(a0*xs0[row] + a1*xs1[row] + gcnb).
__global__ __launch_bounds__(256) void att_combine(
        const u16* __restrict__ xs, const u16* __restrict__ Bt,
        const float* __restrict__ batt, const float* __restrict__ qv,
        const float* __restrict__ gcnb, float* __restrict__ h) {
    __shared__ u16 As[KD][128 * LDSP];
    __shared__ u16 Bs[KD][ATTD * LDSP];
    __shared__ float simbuf[KD][4][64];

    const int tid = threadIdx.x;
    const int lane = tid & 63, waveid = tid >> 6;
    const int wy = waveid >> 1, wx = waveid & 1;
    const int lane15 = lane & 15, quad = lane >> 4;
    const int bm = blockIdx.x * 128;

    floatx4 acc[KD][4][2];
#pragma unroll
    for (int k = 0; k < KD; ++k)
#pragma unroll
        for (int i = 0; i < 4; ++i)
#pragma unroll
            for (int j = 0; j < 2; ++j) acc[k][i][j] = (floatx4){0.f, 0.f, 0.f, 0.f};

    for (int k0 = 0; k0 < DD; k0 += 32) {
        // stage A both k: 128 rows x 32 u16 each (direct bf16 copy)
#pragma unroll
        for (int k = 0; k < KD; ++k) {
#pragma unroll
            for (int t = tid; t < 512; t += 256) {
                int m = t >> 2, ko = (t & 3) << 3;
                uint4 v = make_uint4(0, 0, 0, 0);
                if (bm + m < NN)
                    v = *(const uint4*)(xs + ((size_t)k * NN + bm + m) * DD + k0 + ko);
                *(uint4*)(void*)(As[k] + m * LDSP + ko) = v;
            }
            // stage B: 64 rows x 32 u16
            if (tid < 256) {
                int n = tid >> 2, ko = (tid & 3) << 3;
                uint4 w = *(const uint4*)(Bt + (size_t)k * ATTD * DD + (size_t)n * DD + k0 + ko);
                *(uint4*)(void*)(Bs[k] + n * LDSP + ko) = w;
            }
        }
        __syncthreads();
#pragma unroll
        for (int k = 0; k < KD; ++k) {
            const u16* pA = As[k] + (wy * 64 + lane15) * LDSP + quad * 8;
            const u16* pB = Bs[k] + (wx * 32 + lane15) * LDSP + quad * 8;
            short8 b[2];
            b[0] = *(const short8*)(pB);
            b[1] = *(const short8*)(pB + 16 * LDSP);
#pragma unroll
            for (int i = 0; i < 4; ++i) {
                short8 a = *(const short8*)(pA + i * 16 * LDSP);
                acc[k][i][0] = __builtin_amdgcn_mfma_f32_16x16x32_bf16(a, b[0], acc[k][i][0], 0, 0, 0);
                acc[k][i][1] = __builtin_amdgcn_mfma_f32_16x16x32_bf16(a, b[1], acc[k][i][1], 0, 0, 0);
            }
        }
        __syncthreads();
    }

    // sim reduction: per k, per row: sum_col tanh(acc + batt)*q
#pragma unroll
    for (int k = 0; k < KD; ++k) {
#pragma unroll
        for (int i = 0; i < 4; ++i) {
#pragma unroll
            for (int r = 0; r < 4; ++r) {
                float p = 0.f;
#pragma unroll
                for (int j = 0; j < 2; ++j) {
                    int col = wx * 32 + j * 16 + lane15;
                    float v = acc[k][i][j][r] + batt[k * ATTD + col];
                    p += tanhf(v) * qv[k * ATTD + col];
                }
                p += __shfl_xor(p, 1, 64);
                p += __shfl_xor(p, 2, 64);
                p += __shfl_xor(p, 4, 64);
                p += __shfl_xor(p, 8, 64);
                if (lane15 == 0) simbuf[k][wy * 2 + wx][i * 16 + quad * 4 + r] = p;
            }
        }
    }
    __syncthreads();

    // combine phase: 128 rows x 64 float4-chunks = 8192 items / 256 threads = 32 each
#pragma unroll 4
    for (int it = 0; it < 32; ++it) {
        int item = tid + it * 256;
        int row = item >> 6, dq = item & 63;
        int grow = bm + row;
        if (grow >= NN) continue;
        int wy2 = row >> 6, rl = row & 63;
        float s0 = simbuf[0][wy2 * 2 + 0][rl] + simbuf[0][wy2 * 2 + 1][rl];
        float s1 = simbuf[1][wy2 * 2 + 0][rl] + simbuf[1][wy2 * 2 + 1][rl];
        float m = fmaxf(s0, s1);
        float e0 = __expf(s0 - m), e1 = __expf(s1 - m);
        float inv = 1.f / (e0 + e1);
        float a0 = e0 * inv, a1 = e1 * inv;
        const __hip_bfloat162* p0 = (const __hip_bfloat162*)(xs + (size_t)grow * DD + dq * 4);
        const __hip_bfloat162* p1 = (const __hip_bfloat162*)(xs + ((size_t)NN + grow) * DD + dq * 4);
        float2 v00 = __bfloat1622float2(p0[0]), v01 = __bfloat1622float2(p0[1]);
        float2 v10 = __bfloat1622float2(p1[0]), v11 = __bfloat1622float2(p1[1]);
        float4 bv = ((const float4*)gcnb)[dq];
        float4 r;
        r.x = fmaxf(0.f, a0 * v00.x + a1 * v10.x + bv.x);
        r.y = fmaxf(0.f, a0 * v00.y + a1 * v10.y + bv.y);
        r.z = fmaxf(0.f, a0 * v01.x + a1 * v11.x + bv.z);
        r.w = fmaxf(0.f, a0 * v01.y + a1 * v11.y + bv.w);
        *(float4*)(h + (size_t)grow * DD + dq * 4) = r;
    }
}

extern "C" void kernel_launch(void* const* d_in, const int* in_sizes, int n_in,
                              void* d_out, int out_size, void* d_ws, size_t ws_size,
                              hipStream_t stream) {
    const float* x     = (const float*)d_in[0];
    const int*   ei    = (const int*)d_in[1];
    const float* ew    = (const float*)d_in[2];
    const float* gamma = (const float*)d_in[3];
    const float* beta  = (const float*)d_in[4];
    const float* gcn_W = (const float*)d_in[5];
    const float* gcn_b = (const float*)d_in[6];
    const float* att_W = (const float*)d_in[7];
    const float* att_b = (const float*)d_in[8];
    const float* att_q = (const float*)d_in[9];
    const float* pW1   = (const float*)d_in[10];
    const float* pb1   = (const float*)d_in[11];
    const float* pW2   = (const float*)d_in[12];
    const float* pb2   = (const float*)d_in[13];
    float* out = (float*)d_out;

    char* wsb = (char*)d_ws;
    size_t off = 0;
    auto alloc = [&](size_t bytes) -> void* {
        void* p = wsb + off;
        off += (bytes + 255) & ~(size_t)255;
        return p;
    };
    u16*   xs    = (u16*)alloc((size_t)KD * NN * DD * 2);     // 102.4 MB (bf16)
    float* h     = (float*)alloc((size_t)NN * DD * 4);        // 102.4 MB
    u16*   xw    = (u16*)alloc((size_t)NN * DD * 2);          // 51.2 MB
    float* p1tmp = (float*)xw;                                // N*H1*4, exact reuse
    float* dinv  = (float*)alloc((size_t)KN * 4);
    int*   starts= (int*)alloc(((size_t)KN + 1) * 4);
    int2*  edata = (int2*)alloc((size_t)KD * EE * 8);         // 6.4 MB
    float* bnsums= (float*)alloc(2 * DD * 4);
    u16*   gcnWb = (u16*)alloc((size_t)LL * DD * DD * 2);
    u16*   attWb = (u16*)alloc((size_t)LL * KD * ATTD * DD * 2);
    u16*   pW1b  = (u16*)alloc((size_t)HH1 * DD * 2);
    u16*   pW2b  = (u16*)alloc((size_t)HH2 * HH1 * 2);
    float* batt  = (float*)alloc((size_t)LL * KD * ATTD * 4);
    int*   bsums = (int*)alloc((size_t)SCAN_NB * 4);

    // ---- setup: weight transpose/convert + att bias fold ----
    for (int l = 0; l < LL; ++l)
        wconv<<<(DD * DD + 255) / 256, 256, 0, stream>>>(gcn_W + (size_t)l * DD * DD,
                                                         gcnWb + (size_t)l * DD * DD, DD, DD);
    for (int lk = 0; lk < LL * KD; ++lk)
        wconv<<<(DD * ATTD + 255) / 256, 256, 0, stream>>>(att_W + (size_t)lk * DD * ATTD,
                                                           attWb + (size_t)lk * ATTD * DD, DD, ATTD);
    wconv<<<(DD * HH1 + 255) / 256, 256, 0, stream>>>(pW1, pW1b, DD, HH1);
    wconv<<<(HH1 * HH2 + 255) / 256, 256, 0, stream>>>(pW2, pW2b, HH1, HH2);
    att_bias_fold<<<LL * KD, ATTD, 0, stream>>>(att_W, att_b, gcn_b, batt);

    // ---- BatchNorm -> h ----
    hipMemsetAsync(bnsums, 0, 2 * DD * 4, stream);
    bn_stats<<<800, 256, 0, stream>>>(x, bnsums);
    bn_apply<<<25000, 256, 0, stream>>>(x, bnsums, gamma, beta, h);

    // ---- degree / dinv / CSR (layer-invariant) ----
    hipMemsetAsync(dinv, 0, (size_t)KN * 4, stream);
    deg_accum<<<(KD * EE + 255) / 256, 256, 0, stream>>>(ei, ew, dinv);
    dinv_kernel<<<(KN + 255) / 256, 256, 0, stream>>>(dinv);
    hipMemsetAsync(starts, 0, ((size_t)KN + 1) * 4, stream);
    csr_count<<<(KD * EE + 255) / 256, 256, 0, stream>>>(ei, starts);
    scan_blocks<<<SCAN_NB, 256, 0, stream>>>(starts, bsums);
    scan_sums<<<1, 1024, 0, stream>>>(bsums);
    scan_add<<<SCAN_NB, 256, 0, stream>>>(starts, bsums);
    csr_fill<<<(KD * EE + 255) / 256, 256, 0, stream>>>(ei, ew, dinv, starts, edata);

    const int MB = (NN + 127) / 128;   // 782
    for (int l = 0; l < LL; ++l) {
        gemm_mfma<128, 1, false, 0><<<dim3(MB, DD / 128), 256, 0, stream>>>(
            h, gcnWb + (size_t)l * DD * DD, nullptr, nullptr, xw, NN, DD, DD);
        gather_agg<<<(KN + 3) / 4, 256, 0, stream>>>(starts, edata,
                                                     (const __hip_bfloat16*)xw, xs);
        att_combine<<<MB, 256, 0, stream>>>(
            xs, attWb + (size_t)l * KD * ATTD * DD,
            batt + (size_t)l * KD * ATTD, att_q + (size_t)l * KD * ATTD,
            gcn_b + l * DD, h);
    }

    // ---- projection head ----
    gemm_mfma<128, 0, true, 1><<<dim3(MB, 1), 256, 0, stream>>>(
        h, pW1b, pb1, p1tmp, nullptr, NN, DD, HH1);
    gemm_mfma<64, 0, true, 1><<<dim3(MB, 1), 256, 0, stream>>>(
        p1tmp, pW2b, pb2, out, nullptr, NN, HH1, HH2);
}